// Round 10
// baseline (931.220 us; speedup 1.0000x reference)
//
#include <hip/hip_runtime.h>
#include <math.h>

#define N_NODES 50000
#define N_EDGES 800000
#define NUM_GRAPHS 256
#define NPADROWS 50048   // 1564*32
#define CAP 64           // CSR capacity per node (max observed degree ~35)
#define XR 128           // xf row stride (floats); ch128 lives in x128c
#define XSG 132          // gsum row stride
#define SCLN -1.44269504088896f  // -log2(e): f-side scale, exp2(SCLN*x)=exp(-x)
#define SCLP 1.44269504088896f   // +log2(e): s-side scale
#define C693 0.69314718056f
#define LROW 264         // LDS staging row stride in u16 (528 B)

typedef __attribute__((ext_vector_type(8))) short short8;
typedef __attribute__((ext_vector_type(4))) float f32x4;
typedef __attribute__((ext_vector_type(2))) float f32x2;

__device__ __forceinline__ float fast_rcp(float x) {
#if __has_builtin(__builtin_amdgcn_rcpf)
  return __builtin_amdgcn_rcpf(x);
#else
  return 1.0f / x;
#endif
}
__device__ __forceinline__ float EX2(float x) {
#if __has_builtin(__builtin_amdgcn_exp2f)
  return __builtin_amdgcn_exp2f(x);
#else
  return exp2f(x);
#endif
}
__device__ __forceinline__ float LG2(float x) {
#if __has_builtin(__builtin_amdgcn_logf)
  return __builtin_amdgcn_logf(x);  // log2
#else
  return log2f(x);
#endif
}
__device__ __forceinline__ float LDX(float x, int k) {
#if __has_builtin(__builtin_amdgcn_ldexpf)
  return __builtin_amdgcn_ldexpf(x, k);
#else
  return ldexpf(x, k);
#endif
}
__device__ __forceinline__ unsigned f2bf(float x) {
  unsigned u = __float_as_uint(x);
  return (u + 0x7fffu + ((u >> 16) & 1u)) >> 16;
}
__device__ __forceinline__ float u2f(unsigned u) { return __uint_as_float(u); }
__device__ __forceinline__ f32x2 mk2(float a, float b) {
  f32x2 r; r.x = a; r.y = b; return r;
}
// unpack u32 holding (lo u16 -> ch0 bf16, hi u16 -> ch1 bf16) to f32x2
__device__ __forceinline__ f32x2 unp(unsigned u) {
  return mk2(u2f(u << 16), u2f(u & 0xffff0000u));
}

// ---- packed polynomial transcendentals (v_pk_fma_f32 path, no quarter-rate trans) ----
// exp2: magic round-to-int + deg-5 Taylor (rel err ~3e-6) + ldexp (IEEE inf/0 on overflow)
__device__ __forceinline__ f32x2 pexp2(f32x2 x) {
  const f32x2 MAG = (f32x2)12582912.0f;  // 1.5*2^23
  f32x2 xm = x + MAG;
  f32x2 f = x - (xm - MAG);  // f in [-0.5, 0.5]
  int kx = __float_as_int(xm.x) - 0x4B400000;
  int ky = __float_as_int(xm.y) - 0x4B400000;
  f32x2 p = (f32x2)0.0013333558f;
  p = __builtin_elementwise_fma(p, f, (f32x2)0.0096181291f);
  p = __builtin_elementwise_fma(p, f, (f32x2)0.0555041087f);
  p = __builtin_elementwise_fma(p, f, (f32x2)0.2402265069f);
  p = __builtin_elementwise_fma(p, f, (f32x2)0.6931471806f);
  p = __builtin_elementwise_fma(p, f, (f32x2)1.0f);
  return mk2(LDX(p.x, kx), LDX(p.y, ky));
}
// log2(1+u) for u in [0,1]: deg-8 Taylor about u=0.5 (abs err ~1.2e-5)
__device__ __forceinline__ f32x2 plog21p(f32x2 u) {
  f32x2 t = u + (f32x2)(-0.5f);
  f32x2 p = (f32x2)(-0.0070365f);
  p = __builtin_elementwise_fma(p, t, (f32x2)0.0120625f);
  p = __builtin_elementwise_fma(p, t, (f32x2)(-0.0211095f));
  p = __builtin_elementwise_fma(p, t, (f32x2)0.0379969f);
  p = __builtin_elementwise_fma(p, t, (f32x2)(-0.0712442f));
  p = __builtin_elementwise_fma(p, t, (f32x2)0.1424884f);
  p = __builtin_elementwise_fma(p, t, (f32x2)(-0.3205989f));
  p = __builtin_elementwise_fma(p, t, (f32x2)0.9617967f);
  p = __builtin_elementwise_fma(p, t, (f32x2)0.5849625f);
  return p;
}
// rcp via magic estimate + 2 Newton steps (rel err ~3e-6); den >= 1 here
__device__ __forceinline__ f32x2 prcp(f32x2 d) {
  f32x2 r = mk2(__int_as_float(0x7EF311C3 - __float_as_int(d.x)),
                __int_as_float(0x7EF311C3 - __float_as_int(d.y)));
  f32x2 e = __builtin_elementwise_fma(-d, r, (f32x2)1.0f);
  r = __builtin_elementwise_fma(r, e, r);
  e = __builtin_elementwise_fma(-d, r, (f32x2)1.0f);
  r = __builtin_elementwise_fma(r, e, r);
  return r;
}
// msg pair: sigm (exp2 dom, gf pre-scaled -log2e) * softplus (gs pre-scaled +log2e)
// min(gf,126) only guards the reciprocal against inf (sigmoid there = 2^-126 ~= 0);
// the softplus linear term max(gs,0) is NOT clamped (R5 lesson).
__device__ __forceinline__ void edge_ch2(f32x2 gf, f32x2 gs, float cmul, f32x2& acc) {
  gf = __builtin_elementwise_min(gf, (f32x2)126.0f);
  f32x2 den = pexp2(gf) + 1.0f;
  f32x2 u = pexp2(-__builtin_elementwise_abs(gs));
  f32x2 sp = plog21p(u) + __builtin_elementwise_max(gs, (f32x2)0.0f);
  f32x2 rt = prcp(den) * sp;
  acc = __builtin_elementwise_fma(rt, (f32x2)cmul, acc);
}

// xf rows (128), x128c, bf16 rows, pos4 in one pass (64 thr/node)
__global__ void init_x(const int* __restrict__ atoms, const float* __restrict__ pos,
                       const float* __restrict__ emb, float* __restrict__ xf,
                       float* __restrict__ x128c, unsigned* __restrict__ xbu,
                       float4* __restrict__ pos4) {
  int n = blockIdx.x;
  int t = threadIdx.x;
  int a = atoms[n];
  float2 e = *(const float2*)(emb + (size_t)a * 128 + 2 * t);
  xf[(size_t)n * XR + 2 * t] = e.x;
  xf[(size_t)n * XR + 2 * t + 1] = e.y;
  xbu[(size_t)n * 64 + t] = f2bf(e.x) | (f2bf(e.y) << 16);
  if (t == 0) x128c[n] = pos[n * 3 + 2];
  if (t == 1) pos4[n] = make_float4(pos[3 * n], pos[3 * n + 1], pos[3 * n + 2], 0.f);
}

// B in MFMA fragment order + W128 rank-1 rows, one kernel.
__global__ void prep_b(const float* __restrict__ Wf, const float* __restrict__ Ws,
                       uint4* __restrict__ Bp, float* __restrict__ W128) {
  int idx = blockIdx.x * 256 + threadIdx.x;
  if (idx < 5 * 4 * 9 * 4 * 64) {
    int lane = idx & 63;
    int t = idx >> 6;
    int ks = t & 3; t >>= 2;
    int ct = t % 9; t /= 9;
    int g = t & 3;
    int l = t >> 2;
    const float* W = (g >= 2) ? Ws : Wf;
    int col = ct * 16 + (lane & 15);
    int kb = ks * 32 + (lane >> 4) * 8;
    unsigned u[4];
#pragma unroll
    for (int p = 0; p < 4; ++p) {
      unsigned lo = 0, hi = 0;
      if (col < 129) {
        int k0 = kb + 2 * p, k1 = k0 + 1;
        int r0 = (g & 1) ? 129 + k0 : k0;
        int r1 = (g & 1) ? 129 + k1 : k1;
        lo = f2bf(W[(size_t)(l * 259 + r0) * 129 + col]);
        hi = f2bf(W[(size_t)(l * 259 + r1) * 129 + col]);
      }
      u[p] = lo | (hi << 16);
    }
    Bp[idx] = make_uint4(u[0], u[1], u[2], u[3]);
  } else {
    int j = idx - 5 * 4 * 9 * 4 * 64;
    if (j >= 5 * 4 * 129) return;
    int c = j % 129;
    int t = j / 129;
    int g = t & 3;
    int l = t >> 2;
    const float* W = (g >= 2) ? Ws : Wf;
    int row = (g & 1) ? 257 : 128;
    W128[(l * 4 + g) * 129 + c] = W[(size_t)(l * 259 + row) * 129 + c];
  }
}

__global__ void build_csr(const int* __restrict__ ei, const float4* __restrict__ pos4,
                          int* __restrict__ cnt, int2* __restrict__ csr) {
  int e = blockIdx.x * 256 + threadIdx.x;
  if (e >= N_EDGES) return;
  int s = ei[e];
  int d = ei[N_EDGES + e];
  float4 ps = pos4[s];
  float4 pd = pos4[d];
  float dx = ps.x - pd.x, dy = ps.y - pd.y, dz = ps.z - pd.z;
  float ea = sqrtf(dx * dx + dy * dy + dz * dz);
  int p = atomicAdd(&cnt[d], 1);
  if (p < CAP) csr[d * CAP + p] = make_int2(s, __float_as_int(ea));
}

// graph start offsets from sorted batch; goff[256]=N sentinel
__global__ void offsets_k(const int* __restrict__ batch, int* __restrict__ goff) {
  int n = blockIdx.x * 256 + threadIdx.x;
  if (n > N_NODES) return;
  int b = (n < N_NODES) ? batch[n] : NUM_GRAPHS;
  int bp = (n > 0) ? batch[n - 1] : -1;
  for (int g = bp + 1; g <= b; ++g) goff[g] = n;
}

// 32 rows x (4 groups x 144 cols) per block; wave w = group w.
// f-side (g0,g1) scaled by SCLN; s-side (g2,g3) by SCLP.
// u16 row layout (256 u16): [f(2c),f(2c+1),s(2c),s(2c+1)] at c*4 — Pdh dst, Pfs src.
// ch128: Pd128c[n]=u32(f|s) dst, Pc128[n]=u32(f|s) src. Output staged via LDS.
__global__ __launch_bounds__(256) void gemm_mfma(
    const unsigned* __restrict__ xbu, const float* __restrict__ x128c,
    const uint4* __restrict__ Bp, const float* __restrict__ W128,
    const float* __restrict__ bfL, const float* __restrict__ bsL,
    unsigned short* __restrict__ Pdh, unsigned short* __restrict__ Pfs,
    unsigned* __restrict__ Pd128c, unsigned* __restrict__ Pc128, int layer) {
  __shared__ short smA[32 * 136];  // A staging, row stride 136 shorts
  __shared__ unsigned short ldsD[32 * LROW];  // dst row image (f+s interleaved)
  __shared__ unsigned short ldsS[32 * LROW];  // src row image
  int n0 = blockIdx.x * 32;
  int tid = threadIdx.x;
  for (int ch = tid; ch < 512; ch += 256) {
    int row = ch >> 4, cq = ch & 15;
    *(uint4*)(&smA[row * 136 + cq * 8]) =
        *(const uint4*)(xbu + (size_t)(n0 + row) * 64 + cq * 4);
  }
  __syncthreads();
  int g = tid >> 6;
  int l = tid & 63;
  int q = l >> 4, c16 = l & 15;
  const short8* Bp8 = (const short8*)Bp;
  int bbase = (layer * 4 + g) * 9 * 4;
  f32x4 acc[2][9];
#pragma unroll
  for (int rt = 0; rt < 2; ++rt)
#pragma unroll
    for (int ct = 0; ct < 9; ++ct) acc[rt][ct] = (f32x4){0.f, 0.f, 0.f, 0.f};
#pragma unroll
  for (int ks = 0; ks < 4; ++ks) {
    short8 a0 = *(const short8*)(&smA[c16 * 136 + (ks * 4 + q) * 8]);
    short8 a1 = *(const short8*)(&smA[(16 + c16) * 136 + (ks * 4 + q) * 8]);
#pragma unroll
    for (int ct = 0; ct < 9; ++ct) {
      short8 b = Bp8[(size_t)(bbase + ct * 4 + ks) * 64 + l];
      acc[0][ct] = __builtin_amdgcn_mfma_f32_16x16x32_bf16(a0, b, acc[0][ct], 0, 0, 0);
      acc[1][ct] = __builtin_amdgcn_mfma_f32_16x16x32_bf16(a1, b, acc[1][ct], 0, 0, 0);
    }
  }
  const float* W1g = W128 + (layer * 4 + g) * 129;
  float x128[2][4];
#pragma unroll
  for (int rt = 0; rt < 2; ++rt)
#pragma unroll
    for (int r = 0; r < 4; ++r)
      x128[rt][r] = x128c[n0 + rt * 16 + q * 4 + r];  // contiguous, L1-hit
  float scale = (g < 2) ? SCLN : SCLP;
  unsigned short* ldsO = (g & 1) ? ldsS : ldsD;
  int soff = (g >= 2) ? 2 : 0;
  unsigned short* c128p = (g & 1) ? (unsigned short*)Pc128 : (unsigned short*)Pd128c;
  int c128o = (g >= 2) ? 1 : 0;
#pragma unroll
  for (int ct = 0; ct < 9; ++ct) {
    int col = ct * 16 + c16;
    float w1 = (col <= 128) ? W1g[col] : 0.0f;
    float bias = 0.0f;
    if (g == 0 && col <= 128) bias = bfL[col];
    if (g == 2 && col <= 128) bias = bsL[col];
#pragma unroll
    for (int rt = 0; rt < 2; ++rt) {
#pragma unroll
      for (int r = 0; r < 4; ++r) {
        int rl = rt * 16 + q * 4 + r;  // local row
        float v = scale * (acc[rt][ct][r] + x128[rt][r] * w1 + bias);
        unsigned short bv = (unsigned short)f2bf(v);
        if (col < 128) {
          ldsO[rl * LROW + ((col >> 1) << 2) + soff + (col & 1)] = bv;
        } else if (col == 128) {
          c128p[2 * (size_t)(n0 + rl) + c128o] = bv;
        }
      }
    }
  }
  __syncthreads();
  // coalesced writeback: 2048 16B-chunks (1024 per image), 8 rounds of 256 thr
#pragma unroll
  for (int i = tid; i < 2048; i += 256) {
    int img = i >> 10;
    int c = i & 1023;
    int row = c >> 5, part = c & 31;
    const unsigned short* src = (img ? ldsS : ldsD) + row * LROW + part * 8;
    unsigned short* dst = (img ? Pfs : Pdh) + (size_t)(n0 + row) * 256 + part * 8;
    *(uint4*)dst = *(const uint4*)src;
  }
}

// one wave per dst node. Lanes 0-31: even edges, 32-63: odd edges; each lane 4 channels
// via one uint4 gather. CSR pairs read wave-uniform (scalar pipe) + selects [R8 structure
// — R9's per-half vector CSR load regressed]. Depth-1 prefetch on the gather.
__global__ __launch_bounds__(256) void edge_agg(
    const unsigned short* __restrict__ Pdh, const unsigned short* __restrict__ Pfs,
    const unsigned* __restrict__ Pd128c, const unsigned* __restrict__ Pc128,
    float* __restrict__ xf, float* __restrict__ x128c, unsigned* __restrict__ xbu,
    const int* __restrict__ cnt, const int2* __restrict__ csr,
    const float* __restrict__ WfL, const float* __restrict__ WsL) {
  int lane = threadIdx.x & 63;
  int half = lane >> 5;
  int l5 = lane & 31;
  int n = blockIdx.x * 4 + (threadIdx.x >> 6);
  if (n >= N_NODES) return;
  int nu = __builtin_amdgcn_readfirstlane(n);  // wave-uniform -> scalar pipe
  const float* wfl = WfL + 258 * 129;
  const float* wsl = WsL + 258 * 129;
  uint4 pdv = *(const uint4*)(Pdh + (size_t)nu * 256 + 8 * l5);
  f32x2 bfa = unp(pdv.x), bsa = unp(pdv.y), bfb = unp(pdv.z), bsb = unp(pdv.w);
  float2 wfa0 = *(const float2*)(wfl + 4 * l5);
  float2 wfb0 = *(const float2*)(wfl + 4 * l5 + 2);
  float2 wsa0 = *(const float2*)(wsl + 4 * l5);
  float2 wsb0 = *(const float2*)(wsl + 4 * l5 + 2);
  f32x2 wfa = mk2(SCLN * wfa0.x, SCLN * wfa0.y), wfb = mk2(SCLN * wfb0.x, SCLN * wfb0.y);
  f32x2 wsa = mk2(SCLP * wsa0.x, SCLP * wsa0.y), wsb = mk2(SCLP * wsb0.x, SCLP * wsb0.y);
  unsigned pd1 = Pd128c[nu];
  float bfc8 = u2f(pd1 << 16), bsc8 = u2f(pd1 & 0xffff0000u);
  float wfc8 = SCLN * wfl[128], wsc8 = SCLP * wsl[128];
  int m = cnt[nu];
  if (m > CAP) m = CAP;
  const int4* cb4 = (const int4*)(csr + (size_t)nu * CAP);  // wave-uniform pair load
  const uint4* Pfq = (const uint4*)Pfs;
  float maskC = half ? 0.0f : C693;
  f32x2 accA = (f32x2)0.0f, accB = (f32x2)0.0f;

#define GATHER(qq) Pfq[(size_t)(half ? qq.z : qq.x) * 32 + l5]
#define COMPUTE(qq, gg, CM)                                                    \
  {                                                                            \
    f32x2 ea_ = (f32x2)__int_as_float(half ? qq.w : qq.y);                     \
    edge_ch2(__builtin_elementwise_fma(ea_, wfa, bfa + unp(gg.x)),             \
             __builtin_elementwise_fma(ea_, wsa, bsa + unp(gg.y)), CM, accA);  \
    edge_ch2(__builtin_elementwise_fma(ea_, wfb, bfb + unp(gg.z)),             \
             __builtin_elementwise_fma(ea_, wsb, bsb + unp(gg.w)), CM, accB);  \
  }

  int Pf = m >> 1;
  int4 qc = make_int4(0, 0, 0, 0);
  uint4 gc = make_uint4(0, 0, 0, 0);
  if (Pf > 0) {
    qc = cb4[0];
    gc = GATHER(qc);
  }
  for (int p = 0; p < Pf; ++p) {
    int4 qn = qc;
    uint4 gn = gc;
    if (p + 1 < Pf) {
      qn = cb4[p + 1];
      gn = GATHER(qn);
    }
    COMPUTE(qc, gc, C693);
    qc = qn;
    gc = gn;
  }
  if (m & 1) {  // last edge: both halves compute it, half 1 masked to zero
    int4 qt = cb4[Pf];
    f32x2 ea_ = (f32x2)__int_as_float(qt.y);
    uint4 gt = Pfq[(size_t)qt.x * 32 + l5];
    edge_ch2(__builtin_elementwise_fma(ea_, wfa, bfa + unp(gt.x)),
             __builtin_elementwise_fma(ea_, wsa, bsa + unp(gt.y)), maskC, accA);
    edge_ch2(__builtin_elementwise_fma(ea_, wfb, bfb + unp(gt.z)),
             __builtin_elementwise_fma(ea_, wsb, bsb + unp(gt.w)), maskC, accB);
  }
#undef GATHER
#undef COMPUTE

  // combine halves
  accA.x += __shfl_xor(accA.x, 32, 64);
  accA.y += __shfl_xor(accA.y, 32, 64);
  accB.x += __shfl_xor(accB.x, 32, 64);
  accB.y += __shfl_xor(accB.y, 32, 64);

  // channel 128: lanes parallel over edges (deg <= 64), single u32 gather, reduce
  float v2 = 0.f;
  if (lane < m) {
    int2 se = csr[(size_t)nu * CAP + lane];
    float ea = __int_as_float(se.y);
    unsigned pc = Pc128[se.x];
    float f2 = u2f(pc << 16), s2 = u2f(pc & 0xffff0000u);
    float gf2 = fmaf(ea, wfc8, bfc8 + f2);
    float gs2 = fmaf(ea, wsc8, bsc8 + s2);
    float sp2 = LG2(1.0f + EX2(-fabsf(gs2))) + fmaxf(gs2, 0.0f);
    v2 = C693 * fast_rcp(1.0f + EX2(gf2)) * sp2;
  }
#pragma unroll
  for (int off = 32; off; off >>= 1) v2 += __shfl_down(v2, off, 64);

  size_t xo = (size_t)nu * XR;
  if (half == 0) {
    float4 xv = *(const float4*)(xf + xo + 4 * l5);
    float4 res = make_float4(xv.x + accA.x, xv.y + accA.y, xv.z + accB.x, xv.w + accB.y);
    *(float4*)(xf + xo + 4 * l5) = res;
    *(uint2*)(xbu + (size_t)nu * 64 + 2 * l5) =
        make_uint2(f2bf(res.x) | (f2bf(res.y) << 16), f2bf(res.z) | (f2bf(res.w) << 16));
  }
  if (lane == 0) x128c[nu] += v2;
}

// 4 blocks per graph, partial sums + light atomics; gsum pre-zeroed
__global__ void pool2(const float* __restrict__ xf, const float* __restrict__ x128c,
                      const int* __restrict__ goff, float* __restrict__ gsum) {
  int gph = blockIdx.x >> 2;
  int q = blockIdx.x & 3;
  int t = threadIdx.x;
  if (t >= 129) return;
  int s = goff[gph], e = goff[gph + 1];
  int len = e - s;
  int chunk = (len + 3) >> 2;
  int a = s + q * chunk;
  int b = a + chunk; if (b > e) b = e;
  if (a >= b) return;
  float acc = 0.f;
  if (t < 128) {
    for (int n = a; n < b; ++n) acc += xf[(size_t)n * XR + t];
  } else {
    for (int n = a; n < b; ++n) acc += x128c[n];
  }
  atomicAdd(&gsum[gph * XSG + t], acc);
}

// fused: mean-divide + fc1 + fc2 + fc3 + out. one block per graph, 192 thr.
__global__ void fcout(const float* __restrict__ gsum, const int* __restrict__ goff,
                      const float* __restrict__ Wfc, const float* __restrict__ bfc,
                      const float* __restrict__ Wout, const float* __restrict__ bout,
                      float* __restrict__ out) {
  __shared__ float buf[2][XSG];
  __shared__ float red[3];
  int i = blockIdx.x;
  int t = threadIdx.x;
  int len = goff[i + 1] - goff[i];
  float inv = fast_rcp(fmaxf((float)len, 1.0f));
  if (t < 129) buf[0][t] = gsum[i * XSG + t] * inv;
  __syncthreads();
  int cur = 0;
#pragma unroll
  for (int l = 0; l < 3; ++l) {
    float s = 0.f;
    if (t < 129) {
      s = bfc[l * 129 + t];
      const float* W = Wfc + (size_t)l * 129 * 129;
#pragma unroll 4
      for (int k = 0; k < 129; ++k) s += buf[cur][k] * W[k * 129 + t];
    }
    __syncthreads();
    if (t < 129) buf[1 - cur][t] = s;
    cur = 1 - cur;
    __syncthreads();
  }
  float p = (t < 129) ? buf[cur][t] * Wout[t] : 0.f;
#pragma unroll
  for (int off = 32; off; off >>= 1) p += __shfl_down(p, off, 64);
  if ((t & 63) == 0) red[t >> 6] = p;
  __syncthreads();
  if (t == 0) out[i] = red[0] + red[1] + red[2] + bout[0];
}

extern "C" void kernel_launch(void* const* d_in, const int* in_sizes, int n_in,
                              void* d_out, int out_size, void* d_ws, size_t ws_size,
                              hipStream_t stream) {
  const int* atoms = (const int*)d_in[0];
  const float* pos = (const float*)d_in[1];
  const int* ei = (const int*)d_in[2];
  const int* batch = (const int*)d_in[3];
  const float* emb = (const float*)d_in[4];
  const float* Wf = (const float*)d_in[5];
  const float* bfp = (const float*)d_in[6];
  const float* Ws = (const float*)d_in[7];
  const float* bsp = (const float*)d_in[8];
  const float* Wfc = (const float*)d_in[9];
  const float* bfc = (const float*)d_in[10];
  const float* Wout = (const float*)d_in[11];
  const float* bout = (const float*)d_in[12];
  float* outp = (float*)d_out;

  // workspace layout (every array 16B-aligned by construction)
  uint4* Bp = (uint4*)d_ws;                                   // 46080 uint4
  float* xf = (float*)(Bp + 46080);                           // NPADROWS*128 f32
  float* x128c = xf + (size_t)NPADROWS * XR;                  // NPADROWS f32
  unsigned* xbu = (unsigned*)(x128c + NPADROWS);              // NPADROWS*64 u32
  unsigned short* Pdh = (unsigned short*)(xbu + (size_t)NPADROWS * 64);  // NPADROWS*256
  unsigned short* Pfs = Pdh + (size_t)NPADROWS * 256;         // NPADROWS*256
  float4* pos4 = (float4*)(Pfs + (size_t)NPADROWS * 256);     // N_NODES float4
  float* W128 = (float*)(pos4 + N_NODES);                     // 2580
  float* gsum = W128 + 2580;                                  // 256*XSG
  int* goff = (int*)(gsum + 256 * XSG);                       // 260 (padded)
  int* cnt = goff + 260;                                      // N_NODES
  int2* csr = (int2*)(cnt + N_NODES + 2);                     // N_NODES*CAP (16B-aligned)
  unsigned* Pd128c = (unsigned*)(csr + (size_t)N_NODES * CAP);  // NPADROWS u32
  unsigned* Pc128 = Pd128c + NPADROWS;                        // NPADROWS u32

  hipMemsetAsync(cnt, 0, N_NODES * sizeof(int), stream);
  hipMemsetAsync(gsum, 0, 256 * XSG * sizeof(float), stream);

  init_x<<<N_NODES, 64, 0, stream>>>(atoms, pos, emb, xf, x128c, xbu, pos4);
  prep_b<<<(5 * 4 * 9 * 4 * 64 + 5 * 4 * 129 + 255) / 256, 256, 0, stream>>>(Wf, Ws, Bp,
                                                                             W128);
  build_csr<<<(N_EDGES + 255) / 256, 256, 0, stream>>>(ei, pos4, cnt, csr);
  offsets_k<<<(N_NODES + 256) / 256, 256, 0, stream>>>(batch, goff);

  for (int l = 0; l < 5; ++l) {
    gemm_mfma<<<NPADROWS / 32, 256, 0, stream>>>(xbu, x128c, Bp, W128, bfp + l * 129,
                                                 bsp + l * 129, Pdh, Pfs, Pd128c,
                                                 Pc128, l);
    edge_agg<<<(N_NODES + 3) / 4, 256, 0, stream>>>(Pdh, Pfs, Pd128c, Pc128, xf, x128c,
                                                    xbu, cnt, csr,
                                                    Wf + (size_t)l * 259 * 129,
                                                    Ws + (size_t)l * 259 * 129);
  }

  pool2<<<NUM_GRAPHS * 4, 192, 0, stream>>>(xf, x128c, goff, gsum);
  fcout<<<NUM_GRAPHS, 192, 0, stream>>>(gsum, goff, Wfc, bfc, Wout, bout, outp);
}

// Round 11
// 734.156 us; speedup vs baseline: 1.2684x; 1.2684x over previous
//
#include <hip/hip_runtime.h>
#include <math.h>

#define N_NODES 50000
#define N_EDGES 800000
#define NUM_GRAPHS 256
#define NPADROWS 50048   // 1564*32
#define CAP 64           // CSR capacity per node (max observed degree ~35)
#define XS 132           // xf row stride (floats); [0..127]=emb ch, [128]=z
#define SCLN -1.44269504088896f  // -log2(e): f-side scale, exp2(SCLN*x)=exp(-x)
#define SCLP 1.44269504088896f   // +log2(e): s-side scale
#define C693 0.69314718056f
#define LROW 264         // LDS staging row stride in u16 (528 B)

typedef __attribute__((ext_vector_type(8))) short short8;
typedef __attribute__((ext_vector_type(4))) float f32x4;
typedef __attribute__((ext_vector_type(2))) float f32x2;

__device__ __forceinline__ float fast_rcp(float x) {
#if __has_builtin(__builtin_amdgcn_rcpf)
  return __builtin_amdgcn_rcpf(x);
#else
  return 1.0f / x;
#endif
}
__device__ __forceinline__ float EX2(float x) {
#if __has_builtin(__builtin_amdgcn_exp2f)
  return __builtin_amdgcn_exp2f(x);
#else
  return exp2f(x);
#endif
}
__device__ __forceinline__ float LG2(float x) {
#if __has_builtin(__builtin_amdgcn_logf)
  return __builtin_amdgcn_logf(x);  // log2
#else
  return log2f(x);
#endif
}
__device__ __forceinline__ unsigned f2bf(float x) {
  unsigned u = __float_as_uint(x);
  return (u + 0x7fffu + ((u >> 16) & 1u)) >> 16;
}
__device__ __forceinline__ float u2f(unsigned u) { return __uint_as_float(u); }
__device__ __forceinline__ f32x2 mk2(float a, float b) {
  f32x2 r; r.x = a; r.y = b; return r;
}
// unpack u32 holding (lo u16 -> ch0 bf16, hi u16 -> ch1 bf16) to f32x2
__device__ __forceinline__ f32x2 unp(unsigned u) {
  return mk2(u2f(u << 16), u2f(u & 0xffff0000u));
}
// msg pair: sigm (exp2 dom, gf pre-scaled -log2e) * softplus (gs pre-scaled +log2e)
// HARDWARE trans (R10's polynomial replacement regressed 77->127 us: quarter-rate
// v_exp/v_log/v_rcp are cheaper than the 30+ pk-FMA they'd replace).
__device__ __forceinline__ void edge_ch2(f32x2 gf, f32x2 gs, float cmul, f32x2& acc) {
  f32x2 den = mk2(EX2(gf.x), EX2(gf.y)) + 1.0f;
  f32x2 lg = mk2(LG2(1.0f + EX2(-fabsf(gs.x))), LG2(1.0f + EX2(-fabsf(gs.y))));
  f32x2 sp = lg + __builtin_elementwise_max(gs, (f32x2)0.0f);
  f32x2 rt = mk2(fast_rcp(den.x), fast_rcp(den.y)) * sp;
  acc = __builtin_elementwise_fma(rt, (f32x2)cmul, acc);
}

// xf rows, bf16 rows, and pos4 in one pass (64 thr/node)
__global__ void init_x(const int* __restrict__ atoms, const float* __restrict__ pos,
                       const float* __restrict__ emb, float* __restrict__ xf,
                       unsigned* __restrict__ xbu, float4* __restrict__ pos4) {
  int n = blockIdx.x;
  int t = threadIdx.x;
  int a = atoms[n];
  float2 e = *(const float2*)(emb + (size_t)a * 128 + 2 * t);
  xf[(size_t)n * XS + 2 * t] = e.x;
  xf[(size_t)n * XS + 2 * t + 1] = e.y;
  xbu[(size_t)n * 64 + t] = f2bf(e.x) | (f2bf(e.y) << 16);
  if (t == 0) xf[(size_t)n * XS + 128] = pos[n * 3 + 2];
  if (t == 1) pos4[n] = make_float4(pos[3 * n], pos[3 * n + 1], pos[3 * n + 2], 0.f);
}

// B in MFMA fragment order + W128 rank-1 rows, one kernel.
__global__ void prep_b(const float* __restrict__ Wf, const float* __restrict__ Ws,
                       uint4* __restrict__ Bp, float* __restrict__ W128) {
  int idx = blockIdx.x * 256 + threadIdx.x;
  if (idx < 5 * 4 * 9 * 4 * 64) {
    int lane = idx & 63;
    int t = idx >> 6;
    int ks = t & 3; t >>= 2;
    int ct = t % 9; t /= 9;
    int g = t & 3;
    int l = t >> 2;
    const float* W = (g >= 2) ? Ws : Wf;
    int col = ct * 16 + (lane & 15);
    int kb = ks * 32 + (lane >> 4) * 8;
    unsigned u[4];
#pragma unroll
    for (int p = 0; p < 4; ++p) {
      unsigned lo = 0, hi = 0;
      if (col < 129) {
        int k0 = kb + 2 * p, k1 = k0 + 1;
        int r0 = (g & 1) ? 129 + k0 : k0;
        int r1 = (g & 1) ? 129 + k1 : k1;
        lo = f2bf(W[(size_t)(l * 259 + r0) * 129 + col]);
        hi = f2bf(W[(size_t)(l * 259 + r1) * 129 + col]);
      }
      u[p] = lo | (hi << 16);
    }
    Bp[idx] = make_uint4(u[0], u[1], u[2], u[3]);
  } else {
    int j = idx - 5 * 4 * 9 * 4 * 64;
    if (j >= 5 * 4 * 129) return;
    int c = j % 129;
    int t = j / 129;
    int g = t & 3;
    int l = t >> 2;
    const float* W = (g >= 2) ? Ws : Wf;
    int row = (g & 1) ? 257 : 128;
    W128[(l * 4 + g) * 129 + c] = W[(size_t)(l * 259 + row) * 129 + c];
  }
}

// edge CSR build; threads <= N_NODES also emit graph offsets (merged offsets_k)
__global__ void build_csr(const int* __restrict__ ei, const float4* __restrict__ pos4,
                          const int* __restrict__ batch, int* __restrict__ cnt,
                          int2* __restrict__ csr, int* __restrict__ goff) {
  int e = blockIdx.x * 256 + threadIdx.x;
  if (e <= N_NODES) {
    int b = (e < N_NODES) ? batch[e] : NUM_GRAPHS;
    int bp = (e > 0) ? batch[e - 1] : -1;
    for (int g = bp + 1; g <= b; ++g) goff[g] = e;
  }
  if (e >= N_EDGES) return;
  int s = ei[e];
  int d = ei[N_EDGES + e];
  float4 ps = pos4[s];
  float4 pd = pos4[d];
  float dx = ps.x - pd.x, dy = ps.y - pd.y, dz = ps.z - pd.z;
  float ea = sqrtf(dx * dx + dy * dy + dz * dz);
  int p = atomicAdd(&cnt[d], 1);
  if (p < CAP) csr[d * CAP + p] = make_int2(s, __float_as_int(ea));
}

// 32 rows x (4 groups x 144 cols) per block; wave w = group w.
// f-side (g0,g1) scaled by SCLN; s-side (g2,g3) by SCLP.
// u16 row layout (256 u16): [f(2c),f(2c+1),s(2c),s(2c+1)] at c*4 — Pdh dst, Pfs src.
// ch128: Pd128c[n]=u32(f|s) dst, Pc128[n]=u32(f|s) src. Output staged via LDS.
__global__ __launch_bounds__(256) void gemm_mfma(
    const unsigned* __restrict__ xbu, const float* __restrict__ xf,
    const uint4* __restrict__ Bp, const float* __restrict__ W128,
    const float* __restrict__ bfL, const float* __restrict__ bsL,
    unsigned short* __restrict__ Pdh, unsigned short* __restrict__ Pfs,
    unsigned* __restrict__ Pd128c, unsigned* __restrict__ Pc128, int layer) {
  __shared__ short smA[32 * 136];  // A staging, row stride 136 shorts
  __shared__ unsigned short ldsD[32 * LROW];  // dst row image (f+s interleaved)
  __shared__ unsigned short ldsS[32 * LROW];  // src row image
  int n0 = blockIdx.x * 32;
  int tid = threadIdx.x;
  for (int ch = tid; ch < 512; ch += 256) {
    int row = ch >> 4, cq = ch & 15;
    *(uint4*)(&smA[row * 136 + cq * 8]) =
        *(const uint4*)(xbu + (size_t)(n0 + row) * 64 + cq * 4);
  }
  __syncthreads();
  int g = tid >> 6;
  int l = tid & 63;
  int q = l >> 4, c16 = l & 15;
  const short8* Bp8 = (const short8*)Bp;
  int bbase = (layer * 4 + g) * 9 * 4;
  f32x4 acc[2][9];
#pragma unroll
  for (int rt = 0; rt < 2; ++rt)
#pragma unroll
    for (int ct = 0; ct < 9; ++ct) acc[rt][ct] = (f32x4){0.f, 0.f, 0.f, 0.f};
#pragma unroll
  for (int ks = 0; ks < 4; ++ks) {
    short8 a0 = *(const short8*)(&smA[c16 * 136 + (ks * 4 + q) * 8]);
    short8 a1 = *(const short8*)(&smA[(16 + c16) * 136 + (ks * 4 + q) * 8]);
#pragma unroll
    for (int ct = 0; ct < 9; ++ct) {
      short8 b = Bp8[(size_t)(bbase + ct * 4 + ks) * 64 + l];
      acc[0][ct] = __builtin_amdgcn_mfma_f32_16x16x32_bf16(a0, b, acc[0][ct], 0, 0, 0);
      acc[1][ct] = __builtin_amdgcn_mfma_f32_16x16x32_bf16(a1, b, acc[1][ct], 0, 0, 0);
    }
  }
  const float* W1g = W128 + (layer * 4 + g) * 129;
  float x128[2][4];
#pragma unroll
  for (int rt = 0; rt < 2; ++rt)
#pragma unroll
    for (int r = 0; r < 4; ++r)
      x128[rt][r] = xf[(size_t)(n0 + rt * 16 + q * 4 + r) * XS + 128];
  float scale = (g < 2) ? SCLN : SCLP;
  unsigned short* ldsO = (g & 1) ? ldsS : ldsD;
  int soff = (g >= 2) ? 2 : 0;
  unsigned short* c128p = (g & 1) ? (unsigned short*)Pc128 : (unsigned short*)Pd128c;
  int c128o = (g >= 2) ? 1 : 0;
#pragma unroll
  for (int ct = 0; ct < 9; ++ct) {
    int col = ct * 16 + c16;
    float w1 = (col <= 128) ? W1g[col] : 0.0f;
    float bias = 0.0f;
    if (g == 0 && col <= 128) bias = bfL[col];
    if (g == 2 && col <= 128) bias = bsL[col];
#pragma unroll
    for (int rt = 0; rt < 2; ++rt) {
#pragma unroll
      for (int r = 0; r < 4; ++r) {
        int rl = rt * 16 + q * 4 + r;  // local row
        float v = scale * (acc[rt][ct][r] + x128[rt][r] * w1 + bias);
        unsigned short bv = (unsigned short)f2bf(v);
        if (col < 128) {
          ldsO[rl * LROW + ((col >> 1) << 2) + soff + (col & 1)] = bv;
        } else if (col == 128) {
          c128p[2 * (size_t)(n0 + rl) + c128o] = bv;
        }
      }
    }
  }
  __syncthreads();
  // coalesced writeback: 2048 16B-chunks (1024 per image), 8 rounds of 256 thr
#pragma unroll
  for (int i = tid; i < 2048; i += 256) {
    int img = i >> 10;
    int c = i & 1023;
    int row = c >> 5, part = c & 31;
    const unsigned short* src = (img ? ldsS : ldsD) + row * LROW + part * 8;
    unsigned short* dst = (img ? Pfs : Pdh) + (size_t)(n0 + row) * 256 + part * 8;
    *(uint4*)dst = *(const uint4*)src;
  }
}

// one wave per dst node. Lanes 0-31: even edges, 32-63: odd edges; each lane 4 channels
// via one uint4 gather. Wave-uniform CSR pair loads (scalar pipe) + selects — the
// per-half vector CSR variant (R9) regressed. Depth-1 prefetch on the gather.
__global__ __launch_bounds__(256) void edge_agg(
    const unsigned short* __restrict__ Pdh, const unsigned short* __restrict__ Pfs,
    const unsigned* __restrict__ Pd128c, const unsigned* __restrict__ Pc128,
    float* __restrict__ xf, unsigned* __restrict__ xbu, const int* __restrict__ cnt,
    const int2* __restrict__ csr, const float* __restrict__ WfL,
    const float* __restrict__ WsL) {
  int lane = threadIdx.x & 63;
  int half = lane >> 5;
  int l5 = lane & 31;
  int n = blockIdx.x * 4 + (threadIdx.x >> 6);
  if (n >= N_NODES) return;
  int nu = __builtin_amdgcn_readfirstlane(n);  // wave-uniform -> scalar pipe
  const float* wfl = WfL + 258 * 129;
  const float* wsl = WsL + 258 * 129;
  uint4 pdv = *(const uint4*)(Pdh + (size_t)nu * 256 + 8 * l5);
  f32x2 bfa = unp(pdv.x), bsa = unp(pdv.y), bfb = unp(pdv.z), bsb = unp(pdv.w);
  float2 wfa0 = *(const float2*)(wfl + 4 * l5);
  float2 wfb0 = *(const float2*)(wfl + 4 * l5 + 2);
  float2 wsa0 = *(const float2*)(wsl + 4 * l5);
  float2 wsb0 = *(const float2*)(wsl + 4 * l5 + 2);
  f32x2 wfa = mk2(SCLN * wfa0.x, SCLN * wfa0.y), wfb = mk2(SCLN * wfb0.x, SCLN * wfb0.y);
  f32x2 wsa = mk2(SCLP * wsa0.x, SCLP * wsa0.y), wsb = mk2(SCLP * wsb0.x, SCLP * wsb0.y);
  unsigned pd1 = Pd128c[nu];
  float bfc8 = u2f(pd1 << 16), bsc8 = u2f(pd1 & 0xffff0000u);
  float wfc8 = SCLN * wfl[128], wsc8 = SCLP * wsl[128];
  int m = cnt[nu];
  if (m > CAP) m = CAP;
  const int4* cb4 = (const int4*)(csr + (size_t)nu * CAP);  // wave-uniform pair load
  const uint4* Pfq = (const uint4*)Pfs;
  float maskC = half ? 0.0f : C693;
  f32x2 accA = (f32x2)0.0f, accB = (f32x2)0.0f;

#define GATHER(qq) Pfq[(size_t)(half ? qq.z : qq.x) * 32 + l5]
#define COMPUTE(qq, gg, CM)                                                    \
  {                                                                            \
    f32x2 ea_ = (f32x2)__int_as_float(half ? qq.w : qq.y);                     \
    edge_ch2(__builtin_elementwise_fma(ea_, wfa, bfa + unp(gg.x)),             \
             __builtin_elementwise_fma(ea_, wsa, bsa + unp(gg.y)), CM, accA);  \
    edge_ch2(__builtin_elementwise_fma(ea_, wfb, bfb + unp(gg.z)),             \
             __builtin_elementwise_fma(ea_, wsb, bsb + unp(gg.w)), CM, accB);  \
  }

  int Pf = m >> 1;
  int4 qc = make_int4(0, 0, 0, 0);
  uint4 gc = make_uint4(0, 0, 0, 0);
  if (Pf > 0) {
    qc = cb4[0];
    gc = GATHER(qc);
  }
  for (int p = 0; p < Pf; ++p) {
    int4 qn = qc;
    uint4 gn = gc;
    if (p + 1 < Pf) {
      qn = cb4[p + 1];
      gn = GATHER(qn);
    }
    COMPUTE(qc, gc, C693);
    qc = qn;
    gc = gn;
  }
  if (m & 1) {  // last edge: both halves compute it, half 1 masked to zero
    int4 qt = cb4[Pf];
    f32x2 ea_ = (f32x2)__int_as_float(qt.y);
    uint4 gt = Pfq[(size_t)qt.x * 32 + l5];
    edge_ch2(__builtin_elementwise_fma(ea_, wfa, bfa + unp(gt.x)),
             __builtin_elementwise_fma(ea_, wsa, bsa + unp(gt.y)), maskC, accA);
    edge_ch2(__builtin_elementwise_fma(ea_, wfb, bfb + unp(gt.z)),
             __builtin_elementwise_fma(ea_, wsb, bsb + unp(gt.w)), maskC, accB);
  }
#undef GATHER
#undef COMPUTE

  // combine halves
  accA.x += __shfl_xor(accA.x, 32, 64);
  accA.y += __shfl_xor(accA.y, 32, 64);
  accB.x += __shfl_xor(accB.x, 32, 64);
  accB.y += __shfl_xor(accB.y, 32, 64);

  // channel 128: lanes parallel over edges (deg <= 64), single u32 gather, reduce
  float v2 = 0.f;
  if (lane < m) {
    int2 se = csr[(size_t)nu * CAP + lane];
    float ea = __int_as_float(se.y);
    unsigned pc = Pc128[se.x];
    float f2 = u2f(pc << 16), s2 = u2f(pc & 0xffff0000u);
    float gf2 = fmaf(ea, wfc8, bfc8 + f2);
    float gs2 = fmaf(ea, wsc8, bsc8 + s2);
    float sp2 = LG2(1.0f + EX2(-fabsf(gs2))) + fmaxf(gs2, 0.0f);
    v2 = C693 * fast_rcp(1.0f + EX2(gf2)) * sp2;
  }
#pragma unroll
  for (int off = 32; off; off >>= 1) v2 += __shfl_down(v2, off, 64);

  size_t xo = (size_t)nu * XS;
  if (half == 0) {
    float4 xv = *(const float4*)(xf + xo + 4 * l5);
    float4 res = make_float4(xv.x + accA.x, xv.y + accA.y, xv.z + accB.x, xv.w + accB.y);
    *(float4*)(xf + xo + 4 * l5) = res;
    *(uint2*)(xbu + (size_t)nu * 64 + 2 * l5) =
        make_uint2(f2bf(res.x) | (f2bf(res.y) << 16), f2bf(res.z) | (f2bf(res.w) << 16));
  }
  if (lane == 0) xf[xo + 128] += v2;
}

// 4 blocks per graph, partial sums + light atomics; gsum pre-zeroed
__global__ void pool2(const float* __restrict__ xf, const int* __restrict__ goff,
                      float* __restrict__ gsum) {
  int gph = blockIdx.x >> 2;
  int q = blockIdx.x & 3;
  int t = threadIdx.x;
  if (t >= 129) return;
  int s = goff[gph], e = goff[gph + 1];
  int len = e - s;
  int chunk = (len + 3) >> 2;
  int a = s + q * chunk;
  int b = a + chunk; if (b > e) b = e;
  if (a >= b) return;
  float acc = 0.f;
  for (int n = a; n < b; ++n) acc += xf[(size_t)n * XS + t];
  atomicAdd(&gsum[gph * XS + t], acc);
}

// fused: mean-divide + fc1 + fc2 + fc3 + out. one block per graph, 192 thr.
__global__ void fcout(const float* __restrict__ gsum, const int* __restrict__ goff,
                      const float* __restrict__ Wfc, const float* __restrict__ bfc,
                      const float* __restrict__ Wout, const float* __restrict__ bout,
                      float* __restrict__ out) {
  __shared__ float buf[2][XS];
  __shared__ float red[3];
  int i = blockIdx.x;
  int t = threadIdx.x;
  int len = goff[i + 1] - goff[i];
  float inv = fast_rcp(fmaxf((float)len, 1.0f));
  if (t < 129) buf[0][t] = gsum[i * XS + t] * inv;
  __syncthreads();
  int cur = 0;
#pragma unroll
  for (int l = 0; l < 3; ++l) {
    float s = 0.f;
    if (t < 129) {
      s = bfc[l * 129 + t];
      const float* W = Wfc + (size_t)l * 129 * 129;
#pragma unroll 4
      for (int k = 0; k < 129; ++k) s += buf[cur][k] * W[k * 129 + t];
    }
    __syncthreads();
    if (t < 129) buf[1 - cur][t] = s;
    cur = 1 - cur;
    __syncthreads();
  }
  float p = (t < 129) ? buf[cur][t] * Wout[t] : 0.f;
#pragma unroll
  for (int off = 32; off; off >>= 1) p += __shfl_down(p, off, 64);
  if ((t & 63) == 0) red[t >> 6] = p;
  __syncthreads();
  if (t == 0) out[i] = red[0] + red[1] + red[2] + bout[0];
}

extern "C" void kernel_launch(void* const* d_in, const int* in_sizes, int n_in,
                              void* d_out, int out_size, void* d_ws, size_t ws_size,
                              hipStream_t stream) {
  const int* atoms = (const int*)d_in[0];
  const float* pos = (const float*)d_in[1];
  const int* ei = (const int*)d_in[2];
  const int* batch = (const int*)d_in[3];
  const float* emb = (const float*)d_in[4];
  const float* Wf = (const float*)d_in[5];
  const float* bfp = (const float*)d_in[6];
  const float* Ws = (const float*)d_in[7];
  const float* bsp = (const float*)d_in[8];
  const float* Wfc = (const float*)d_in[9];
  const float* bfc = (const float*)d_in[10];
  const float* Wout = (const float*)d_in[11];
  const float* bout = (const float*)d_in[12];
  float* outp = (float*)d_out;

  // workspace layout (every array 16B-aligned by construction)
  uint4* Bp = (uint4*)d_ws;                                   // 46080 uint4
  float* xf = (float*)(Bp + 46080);                           // NPADROWS*132 f32
  unsigned* xbu = (unsigned*)(xf + (size_t)NPADROWS * XS);    // NPADROWS*64 u32
  unsigned short* Pdh = (unsigned short*)(xbu + (size_t)NPADROWS * 64);  // NPADROWS*256
  unsigned short* Pfs = Pdh + (size_t)NPADROWS * 256;         // NPADROWS*256
  float4* pos4 = (float4*)(Pfs + (size_t)NPADROWS * 256);     // N_NODES float4
  float* W128 = (float*)(pos4 + N_NODES);                     // 2580
  float* gsum = W128 + 2580;                                  // 256*XS
  int* goff = (int*)(gsum + 256 * XS);                        // 260 (padded)
  int* cnt = goff + 260;                                      // N_NODES
  int2* csr = (int2*)(cnt + N_NODES + 2);                     // N_NODES*CAP (16B-aligned)
  unsigned* Pd128c = (unsigned*)(csr + (size_t)N_NODES * CAP);  // NPADROWS u32
  unsigned* Pc128 = Pd128c + NPADROWS;                        // NPADROWS u32

  hipMemsetAsync(cnt, 0, N_NODES * sizeof(int), stream);
  hipMemsetAsync(gsum, 0, 256 * XS * sizeof(float), stream);

  init_x<<<N_NODES, 64, 0, stream>>>(atoms, pos, emb, xf, xbu, pos4);
  prep_b<<<(5 * 4 * 9 * 4 * 64 + 5 * 4 * 129 + 255) / 256, 256, 0, stream>>>(Wf, Ws, Bp,
                                                                             W128);
  build_csr<<<(N_EDGES + 255) / 256, 256, 0, stream>>>(ei, pos4, batch, cnt, csr, goff);

  for (int l = 0; l < 5; ++l) {
    gemm_mfma<<<NPADROWS / 32, 256, 0, stream>>>(xbu, xf, Bp, W128, bfp + l * 129,
                                                 bsp + l * 129, Pdh, Pfs, Pd128c,
                                                 Pc128, l);
    edge_agg<<<(N_NODES + 3) / 4, 256, 0, stream>>>(Pdh, Pfs, Pd128c, Pc128, xf, xbu,
                                                    cnt, csr,
                                                    Wf + (size_t)l * 259 * 129,
                                                    Ws + (size_t)l * 259 * 129);
  }

  pool2<<<NUM_GRAPHS * 4, 192, 0, stream>>>(xf, goff, gsum);
  fcout<<<NUM_GRAPHS, 192, 0, stream>>>(gsum, goff, Wfc, bfc, Wout, bout, outp);
}